// Round 4
// baseline (46.976 us; speedup 1.0000x reference)
//
#include <hip/hip_runtime.h>

#define EPS 1e-7f
#define NB 64
#define NI 1152
#define NJ 8
#define NK 43
#define NL 16
#define THREADS 768
#define CHUNK 576
#define NCHUNK 2          // NI / CHUNK
#define NKG 11            // groups of 4 k's (44 = NK+1 pad)
#define GTHREADS 704      // NKG * 64 (one wave per kg)
#define GITER 9           // CHUNK / 64
#define CPSTRIDE 580      // float4 row stride for cP (576 + 4 pad)
#define GPSTRIDE 33       // float row stride for Gp (32 + 1 -> odd, conflict-free)

__global__ __launch_bounds__(THREADS, 1)
void capsule_routing_kernel(const float* __restrict__ X, const float* __restrict__ W,
                            float* __restrict__ out) {
    __shared__ __align__(16) float sW[NJ*NK*NL];      // 22,016 B
    __shared__ __align__(16) float uShared[NKG*CPSTRIDE*4]; // 102,080 B: cP / Gp / xsP alias
    __shared__ __align__(16) float sWv[NJ][44];       //  1,408 B
    __shared__ float sV[NK][NL];
    __shared__ float sS[NK][NL];
    __shared__ float sG[NK*NJ];
    __shared__ float sXs[NJ];

    float4* cP  = (float4*)uShared;                   // [NKG][CPSTRIDE]
    float*  Gp  = uShared;                            // [GTHREADS][GPSTRIDE]
    float*  xsP = uShared;                            // [NJ][96]

    const int tid = threadIdx.x;
    const int b = blockIdx.x;
    const float* Xb = X + (size_t)b * (NI*NJ);
    const float4* Xb4 = (const float4*)Xb;

    // ---- load W into LDS ----
    {
        const float4* W4 = (const float4*)W;
        float4* sW4 = (float4*)sW;
        for (int t = tid; t < (NJ*NK*NL)/4; t += THREADS) sW4[t] = W4[t];
    }
    // ---- xs[j] = sum_i x[i][j] (global reads, 8 j-groups x 96 subs) ----
    {
        const int j = tid / 96, sub = tid % 96;
        float p = 0.f;
        #pragma unroll
        for (int ii = 0; ii < NI/96; ++ii) p += Xb[(sub + 96*ii)*8 + j];
        xsP[j*96 + sub] = p;
    }
    __syncthreads();
    if (tid < NJ) {
        float s = 0.f;
        for (int q = 0; q < 96; ++q) s += xsP[tid*96 + q];
        sXs[tid] = s;
    }
    __syncthreads();
    // ---- s0 = (1/43) * xs . W ----
    if (tid < NK*NL) {
        float s = 0.f;
        #pragma unroll
        for (int j = 0; j < NJ; ++j) s += sXs[j] * sW[j*NK*NL + tid];
        sS[tid >> 4][tid & 15] = s * (1.0f/43.0f);
    }
    __syncthreads();
    // ---- squash -> v0 ----
    if (tid < NK) {
        float s2 = 0.f;
        #pragma unroll
        for (int l = 0; l < NL; ++l) { float v = sS[tid][l]; s2 += v*v; }
        float scale = s2 / ((1.f + s2) * sqrtf(s2 + EPS));
        #pragma unroll
        for (int l = 0; l < NL; ++l) sV[tid][l] = scale * sS[tid][l];
    }
    if (tid < NJ) sWv[tid][43] = 0.f;
    __syncthreads();
    // ---- Wv0[j,k] = sum_l W[j,k,l]*v0[k,l] ----
    if (tid < 352) {
        const int j = tid / 44, k = tid % 44;
        if (k < NK) {
            float wv = 0.f;
            #pragma unroll
            for (int l = 0; l < NL; ++l) wv += sW[j*NK*NL + k*NL + l] * sV[k][l];
            sWv[j][k] = wv;
        }
    }
    __syncthreads();

    // ---- routing passes r=1, r=2 ----
    for (int pass = 0; pass < 2; ++pass) {
        float acc[4][8];
        #pragma unroll
        for (int q = 0; q < 4; ++q)
            #pragma unroll
            for (int j = 0; j < 8; ++j) acc[q][j] = 0.f;

        for (int chunk = 0; chunk < NCHUNK; ++chunk) {
            // ---- Phase A: logits + softmax, one i per thread (tid<576) ----
            float a[44];
            if (tid < CHUNK) {
                const int i = chunk*CHUNK + tid;
                float4 x0 = Xb4[i*2], x1 = Xb4[i*2 + 1];
                float xr[NJ] = {x0.x, x0.y, x0.z, x0.w, x1.x, x1.y, x1.z, x1.w};
                #pragma unroll
                for (int k = 0; k < 44; ++k) a[k] = 0.f;
                #pragma unroll
                for (int j = 0; j < NJ; ++j) {
                    #pragma unroll
                    for (int k4 = 0; k4 < 11; ++k4) {
                        float4 wv = *(const float4*)&sWv[j][k4*4];
                        a[k4*4+0] = fmaf(xr[j], wv.x, a[k4*4+0]);
                        a[k4*4+1] = fmaf(xr[j], wv.y, a[k4*4+1]);
                        a[k4*4+2] = fmaf(xr[j], wv.z, a[k4*4+2]);
                        a[k4*4+3] = fmaf(xr[j], wv.w, a[k4*4+3]);
                    }
                }
                // 4-lane max tree (fusable to v_max3)
                float m0=a[0], m1=a[1], m2=a[2], m3=a[3];
                #pragma unroll
                for (int k = 4; k < 40; k += 4) {
                    m0 = fmaxf(m0, a[k+0]); m1 = fmaxf(m1, a[k+1]);
                    m2 = fmaxf(m2, a[k+2]); m3 = fmaxf(m3, a[k+3]);
                }
                m0 = fmaxf(m0, a[40]); m1 = fmaxf(m1, a[41]); m2 = fmaxf(m2, a[42]);
                const float m = fmaxf(fmaxf(m0, m1), fmaxf(m2, m3));
                float z0=0.f, z1=0.f, z2=0.f, z3=0.f;
                #pragma unroll
                for (int k = 0; k < 40; k += 4) {
                    a[k+0] = __expf(a[k+0]-m); z0 += a[k+0];
                    a[k+1] = __expf(a[k+1]-m); z1 += a[k+1];
                    a[k+2] = __expf(a[k+2]-m); z2 += a[k+2];
                    a[k+3] = __expf(a[k+3]-m); z3 += a[k+3];
                }
                a[40] = __expf(a[40]-m); z0 += a[40];
                a[41] = __expf(a[41]-m); z1 += a[41];
                a[42] = __expf(a[42]-m); z2 += a[42];
                const float inv = 1.f / ((z0+z1) + (z2+z3));
                #pragma unroll
                for (int k = 0; k < NK; ++k) a[k] *= inv;
                a[43] = 0.f;
            }
            __syncthreads();   // previous consumers of cP/Gp region done
            if (tid < CHUNK) {
                #pragma unroll
                for (int kg = 0; kg < NKG; ++kg)
                    cP[kg*CPSTRIDE + tid] = make_float4(a[4*kg], a[4*kg+1], a[4*kg+2], a[4*kg+3]);
            }
            __syncthreads();   // cP ready
            // ---- Phase B: register-blocked G accumulate (tid<704, wave-per-kg) ----
            if (tid < GTHREADS) {
                const int kg = tid >> 6, s = tid & 63;
                #pragma unroll
                for (int ii = 0; ii < GITER; ++ii) {
                    const int il = s + 64*ii;
                    float4 c4 = cP[kg*CPSTRIDE + il];
                    const int gi = chunk*CHUNK + il;
                    float4 xa = Xb4[gi*2], xb = Xb4[gi*2 + 1];
                    acc[0][0]=fmaf(c4.x,xa.x,acc[0][0]); acc[0][1]=fmaf(c4.x,xa.y,acc[0][1]);
                    acc[0][2]=fmaf(c4.x,xa.z,acc[0][2]); acc[0][3]=fmaf(c4.x,xa.w,acc[0][3]);
                    acc[0][4]=fmaf(c4.x,xb.x,acc[0][4]); acc[0][5]=fmaf(c4.x,xb.y,acc[0][5]);
                    acc[0][6]=fmaf(c4.x,xb.z,acc[0][6]); acc[0][7]=fmaf(c4.x,xb.w,acc[0][7]);
                    acc[1][0]=fmaf(c4.y,xa.x,acc[1][0]); acc[1][1]=fmaf(c4.y,xa.y,acc[1][1]);
                    acc[1][2]=fmaf(c4.y,xa.z,acc[1][2]); acc[1][3]=fmaf(c4.y,xa.w,acc[1][3]);
                    acc[1][4]=fmaf(c4.y,xb.x,acc[1][4]); acc[1][5]=fmaf(c4.y,xb.y,acc[1][5]);
                    acc[1][6]=fmaf(c4.y,xb.z,acc[1][6]); acc[1][7]=fmaf(c4.y,xb.w,acc[1][7]);
                    acc[2][0]=fmaf(c4.z,xa.x,acc[2][0]); acc[2][1]=fmaf(c4.z,xa.y,acc[2][1]);
                    acc[2][2]=fmaf(c4.z,xa.z,acc[2][2]); acc[2][3]=fmaf(c4.z,xa.w,acc[2][3]);
                    acc[2][4]=fmaf(c4.z,xb.x,acc[2][4]); acc[2][5]=fmaf(c4.z,xb.y,acc[2][5]);
                    acc[2][6]=fmaf(c4.z,xb.z,acc[2][6]); acc[2][7]=fmaf(c4.z,xb.w,acc[2][7]);
                    acc[3][0]=fmaf(c4.w,xa.x,acc[3][0]); acc[3][1]=fmaf(c4.w,xa.y,acc[3][1]);
                    acc[3][2]=fmaf(c4.w,xa.z,acc[3][2]); acc[3][3]=fmaf(c4.w,xa.w,acc[3][3]);
                    acc[3][4]=fmaf(c4.w,xb.x,acc[3][4]); acc[3][5]=fmaf(c4.w,xb.y,acc[3][5]);
                    acc[3][6]=fmaf(c4.w,xb.z,acc[3][6]); acc[3][7]=fmaf(c4.w,xb.w,acc[3][7]);
                }
            }
        }
        __syncthreads();   // B done reading cP; region reusable as Gp
        if (tid < GTHREADS) {
            #pragma unroll
            for (int q = 0; q < 4; ++q)
                #pragma unroll
                for (int j = 0; j < 8; ++j)
                    Gp[tid*GPSTRIDE + q*8 + j] = acc[q][j];
        }
        __syncthreads();
        // ---- reduce 64 slices -> sG[k*8+j] ----
        if (tid < NK*NJ) {
            const int k = tid >> 3, j = tid & 7;
            const int kg = k >> 2, k4 = k & 3;
            float g = 0.f;
            for (int s = 0; s < 64; ++s) g += Gp[(kg*64 + s)*GPSTRIDE + k4*8 + j];
            sG[tid] = g;
        }
        __syncthreads();
        // ---- s[k,l] = sum_j G[k,j] * W[j,k,l] ----
        if (tid < NK*NL) {
            const int k = tid >> 4;
            float s = 0.f;
            #pragma unroll
            for (int j = 0; j < NJ; ++j) s = fmaf(sG[k*8+j], sW[j*NK*NL + tid], s);
            sS[k][tid & 15] = s;
        }
        __syncthreads();
        // ---- squash -> v ----
        if (tid < NK) {
            float s2 = 0.f;
            #pragma unroll
            for (int l = 0; l < NL; ++l) { float v = sS[tid][l]; s2 += v*v; }
            float scale = s2 / ((1.f + s2) * sqrtf(s2 + EPS));
            #pragma unroll
            for (int l = 0; l < NL; ++l) sV[tid][l] = scale * sS[tid][l];
        }
        __syncthreads();
        if (pass == 0) {
            if (tid < 352) {
                const int j = tid / 44, k = tid % 44;
                if (k < NK) {
                    float wv = 0.f;
                    #pragma unroll
                    for (int l = 0; l < NL; ++l) wv += sW[j*NK*NL + k*NL + l] * sV[k][l];
                    sWv[j][k] += wv;
                }
            }
        } else {
            if (tid < NK*NL)
                out[(size_t)b*NK*NL + tid] = sV[tid >> 4][tid & 15];
        }
        __syncthreads();   // protect sWv (next pass A) / cP region
    }
}

extern "C" void kernel_launch(void* const* d_in, const int* in_sizes, int n_in,
                              void* d_out, int out_size, void* d_ws, size_t ws_size,
                              hipStream_t stream) {
    const float* X = (const float*)d_in[0];   // [64,1152,8]
    const float* W = (const float*)d_in[1];   // [8,43,16]
    float* out = (float*)d_out;               // [64,43,16]
    hipLaunchKernelGGL(capsule_routing_kernel, dim3(NB), dim3(THREADS), 0, stream,
                       X, W, out);
}